// Round 1
// baseline (164.987 us; speedup 1.0000x reference)
//
#include <hip/hip_runtime.h>
#include <math.h>

typedef unsigned short u16;
typedef unsigned int u32;
typedef __attribute__((ext_vector_type(4))) float f32x4;
typedef __attribute__((ext_vector_type(8))) short bf16x8;

#define NP 16
#define DLAT 768
#define HDIM 3072
#define NB 256
#define MAXO 250
#define TOT 2800
#define NKPAD 40

__device__ inline u16 f2b(float f) {
  union { float f; u32 u; } v; v.f = f;
  u32 u = v.u;
  u32 r = (u + 0x7fffu + ((u >> 16) & 1u)) >> 16;
  return (u16)r;
}

// ---------------- LayerNorm: x[B,P,D] fp32 -> xn[P,B,D] bf16 ----------------
__global__ __launch_bounds__(256) void ln_kernel(
    const float* __restrict__ x, const float* __restrict__ gamma,
    const float* __restrict__ beta, u16* __restrict__ xn) {
  const int wave = threadIdx.x >> 6, lane = threadIdx.x & 63;
  const int row = blockIdx.x * 4 + wave;         // 0..4095 = b*16+p
  const int b = row >> 4, p = row & 15;
  const float4* xr = (const float4*)(x + (size_t)row * DLAT);
  const float4* g4 = (const float4*)(gamma + (size_t)p * DLAT);
  const float4* b4 = (const float4*)(beta + (size_t)p * DLAT);
  float4 v[3];
  float s = 0.f, ss = 0.f;
#pragma unroll
  for (int j = 0; j < 3; ++j) {
    v[j] = xr[lane + j * 64];
    s += v[j].x + v[j].y + v[j].z + v[j].w;
    ss += v[j].x * v[j].x + v[j].y * v[j].y + v[j].z * v[j].z + v[j].w * v[j].w;
  }
#pragma unroll
  for (int o = 32; o; o >>= 1) { s += __shfl_xor(s, o); ss += __shfl_xor(ss, o); }
  const float mu = s * (1.f / 768.f);
  const float var = ss * (1.f / 768.f) - mu * mu;
  const float rstd = rsqrtf(var + 1e-5f);
  u16* xo = xn + ((size_t)(p * NB + b)) * DLAT;
#pragma unroll
  for (int j = 0; j < 3; ++j) {
    const int f = lane + j * 64;
    float4 g = g4[f], be = b4[f];
    float o0 = (v[j].x - mu) * rstd * g.x + be.x;
    float o1 = (v[j].y - mu) * rstd * g.y + be.y;
    float o2 = (v[j].z - mu) * rstd * g.z + be.z;
    float o3 = (v[j].w - mu) * rstd * g.w + be.w;
    uint2 w;
    w.x = (u32)f2b(o0) | ((u32)f2b(o1) << 16);
    w.y = (u32)f2b(o2) | ((u32)f2b(o3) << 16);
    *(uint2*)&xo[f * 4] = w;
  }
}

// ---------------- fc1: h = GELU(xn @ w1^T)  per part ----------------
// BM=256 (all M, w1 read once), BN=64, BK=32. 256 thr = 4 waves, wave w -> rows [64w,64w+64)
__global__ __launch_bounds__(256) void fc1_kernel(
    const u16* __restrict__ xn, const float* __restrict__ w1, u16* __restrict__ h) {
  const int bx = blockIdx.x;
  const int p = bx / 48;
  const int n0 = (bx % 48) * 64;
  const int tid = threadIdx.x;
  const int lane = tid & 63;
  const int wave = tid >> 6;

  const u16* Ap = xn + (size_t)p * NB * DLAT;
  const float* Bp = w1 + (size_t)p * HDIM * DLAT + (size_t)n0 * DLAT;

  __shared__ u16 As[2][256][NKPAD];
  __shared__ u16 Bs[2][64][NKPAD];

  const int arow = tid >> 2;          // +64*i
  const int akc = (tid & 3) * 8;
  const int brow = tid >> 3;          // +32*i
  const int bkc = (tid & 7) * 4;

  f32x4 acc[4][4] = {};
  uint4 aregs[4];
  float4 bregs[2];

  auto LOAD = [&](int k0) {
#pragma unroll
    for (int i = 0; i < 4; ++i)
      aregs[i] = *(const uint4*)(Ap + (size_t)(arow + 64 * i) * DLAT + k0 + akc);
#pragma unroll
    for (int i = 0; i < 2; ++i)
      bregs[i] = *(const float4*)(Bp + (size_t)(brow + 32 * i) * DLAT + k0 + bkc);
  };
  auto STORE = [&](int buf) {
#pragma unroll
    for (int i = 0; i < 4; ++i)
      *(uint4*)&As[buf][arow + 64 * i][akc] = aregs[i];
#pragma unroll
    for (int i = 0; i < 2; ++i) {
      uint2 w;
      w.x = (u32)f2b(bregs[i].x) | ((u32)f2b(bregs[i].y) << 16);
      w.y = (u32)f2b(bregs[i].z) | ((u32)f2b(bregs[i].w) << 16);
      *(uint2*)&Bs[buf][brow + 32 * i][bkc] = w;
    }
  };

  LOAD(0);
  STORE(0);
  __syncthreads();

  const int NK = DLAT / 32;  // 24
  for (int kt = 0; kt < NK; ++kt) {
    const int cur = kt & 1;
    if (kt + 1 < NK) LOAD((kt + 1) * 32);
    bf16x8 af[4], bf[4];
#pragma unroll
    for (int m = 0; m < 4; ++m)
      af[m] = *(const bf16x8*)&As[cur][wave * 64 + m * 16 + (lane & 15)][(lane >> 4) * 8];
#pragma unroll
    for (int n = 0; n < 4; ++n)
      bf[n] = *(const bf16x8*)&Bs[cur][n * 16 + (lane & 15)][(lane >> 4) * 8];
#pragma unroll
    for (int m = 0; m < 4; ++m)
#pragma unroll
      for (int n = 0; n < 4; ++n)
        acc[m][n] = __builtin_amdgcn_mfma_f32_16x16x32_bf16(af[m], bf[n], acc[m][n], 0, 0, 0);
    if (kt + 1 < NK) STORE(cur ^ 1);
    __syncthreads();
  }

  // epilogue: exact GELU, store bf16
  u16* hp = h + (size_t)p * NB * HDIM;
#pragma unroll
  for (int m = 0; m < 4; ++m) {
#pragma unroll
    for (int n = 0; n < 4; ++n) {
      const int col = n0 + n * 16 + (lane & 15);
#pragma unroll
      for (int r = 0; r < 4; ++r) {
        const int row = wave * 64 + m * 16 + (lane >> 4) * 4 + r;
        const float vv = acc[m][n][r];
        const float gel = 0.5f * vv * (1.f + erff(vv * 0.70710678118654752f));
        hp[(size_t)row * HDIM + col] = f2b(gel);
      }
    }
  }
}

// ---------------- fc2: out = h @ w2^T + b2, concat slices ----------------
// BM=64, BN=64, BK=32, 256 thr = 4 waves in 2x2, each wave 32x32
__global__ __launch_bounds__(256) void fc2_kernel(
    const u16* __restrict__ h, const float* __restrict__ w2,
    const float* __restrict__ b2, float* __restrict__ out) {
  const int bx = blockIdx.x;
  const int p = bx >> 4;
  const int mb = (bx >> 2) & 3;
  const int nb = bx & 3;
  const int odim = 100 + 10 * p;
  const int n0 = nb * 64;
  if (n0 >= odim) return;                  // fully masked N-block (uniform)
  const int m0 = mb * 64;
  const int off = 100 * p + 5 * p * (p - 1);

  const int tid = threadIdx.x;
  const int lane = tid & 63;
  const int wave = tid >> 6;
  const int wr = wave >> 1, wc = wave & 1;

  const u16* Ap = h + (size_t)p * NB * HDIM + (size_t)m0 * HDIM;
  const float* Bp = w2 + (size_t)p * MAXO * HDIM;

  __shared__ u16 As[2][64][NKPAD];
  __shared__ u16 Bs[2][64][NKPAD];

  const int arow = tid >> 2;          // 0..63
  const int akc = (tid & 3) * 8;
  const int brow = tid >> 3;          // +32*i
  const int bkc = (tid & 7) * 4;
  // clamp w2 row reads so we never run past the allocation (padding rows are garbage, masked on store)
  const int brg0 = min(n0 + brow, MAXO - 1);
  const int brg1 = min(n0 + brow + 32, MAXO - 1);

  f32x4 acc[2][2] = {};
  uint4 areg;
  float4 bregs[2];

  auto LOAD = [&](int k0) {
    areg = *(const uint4*)(Ap + (size_t)arow * HDIM + k0 + akc);
    bregs[0] = *(const float4*)(Bp + (size_t)brg0 * HDIM + k0 + bkc);
    bregs[1] = *(const float4*)(Bp + (size_t)brg1 * HDIM + k0 + bkc);
  };
  auto STORE = [&](int buf) {
    *(uint4*)&As[buf][arow][akc] = areg;
#pragma unroll
    for (int i = 0; i < 2; ++i) {
      uint2 w;
      w.x = (u32)f2b(bregs[i].x) | ((u32)f2b(bregs[i].y) << 16);
      w.y = (u32)f2b(bregs[i].z) | ((u32)f2b(bregs[i].w) << 16);
      *(uint2*)&Bs[buf][brow + 32 * i][bkc] = w;
    }
  };

  LOAD(0);
  STORE(0);
  __syncthreads();

  const int NK = HDIM / 32;  // 96
  for (int kt = 0; kt < NK; ++kt) {
    const int cur = kt & 1;
    if (kt + 1 < NK) LOAD((kt + 1) * 32);
    bf16x8 af[2], bf[2];
#pragma unroll
    for (int m = 0; m < 2; ++m)
      af[m] = *(const bf16x8*)&As[cur][wr * 32 + m * 16 + (lane & 15)][(lane >> 4) * 8];
#pragma unroll
    for (int n = 0; n < 2; ++n)
      bf[n] = *(const bf16x8*)&Bs[cur][wc * 32 + n * 16 + (lane & 15)][(lane >> 4) * 8];
#pragma unroll
    for (int m = 0; m < 2; ++m)
#pragma unroll
      for (int n = 0; n < 2; ++n)
        acc[m][n] = __builtin_amdgcn_mfma_f32_16x16x32_bf16(af[m], bf[n], acc[m][n], 0, 0, 0);
    if (kt + 1 < NK) STORE(cur ^ 1);
    __syncthreads();
  }

  // epilogue: bias + masked store into concatenated output
#pragma unroll
  for (int m = 0; m < 2; ++m) {
#pragma unroll
    for (int n = 0; n < 2; ++n) {
      const int col = n0 + wc * 32 + n * 16 + (lane & 15);
      if (col < odim) {
        const float bias = b2[(size_t)p * MAXO + col];
#pragma unroll
        for (int r = 0; r < 4; ++r) {
          const int row = m0 + wr * 32 + m * 16 + (lane >> 4) * 4 + r;
          out[(size_t)row * TOT + off + col] = acc[m][n][r] + bias;
        }
      }
    }
  }
}

extern "C" void kernel_launch(void* const* d_in, const int* in_sizes, int n_in,
                              void* d_out, int out_size, void* d_ws, size_t ws_size,
                              hipStream_t stream) {
  const float* x = (const float*)d_in[0];
  const float* gamma = (const float*)d_in[1];
  const float* beta = (const float*)d_in[2];
  const float* w1 = (const float*)d_in[3];
  const float* w2 = (const float*)d_in[4];
  const float* b2 = (const float*)d_in[5];
  float* out = (float*)d_out;

  u16* xn = (u16*)d_ws;                             // [16][256][768] bf16  (6.3 MB)
  u16* h = (u16*)d_ws + (size_t)NP * NB * DLAT;     // [16][256][3072] bf16 (25.2 MB)

  ln_kernel<<<1024, 256, 0, stream>>>(x, gamma, beta, xn);
  fc1_kernel<<<NP * 48, 256, 0, stream>>>(xn, w1, h);
  fc2_kernel<<<NP * 16, 256, 0, stream>>>(h, w2, b2, out);
}

// Round 2
// 109.387 us; speedup vs baseline: 1.5083x; 1.5083x over previous
//
#include <hip/hip_runtime.h>
#include <math.h>

typedef unsigned short u16;
typedef unsigned int u32;
typedef __attribute__((ext_vector_type(4))) float f32x4;
typedef __attribute__((ext_vector_type(8))) short bf16x8;

#define NP 16
#define DLAT 768
#define HDIM 3072
#define NB 256
#define MAXO 250
#define TOT 2800

__device__ __forceinline__ u16 f2b(float f) {
  union { float f; u32 u; } v; v.f = f;
  u32 u = v.u;
  u32 r = (u + 0x7fffu + ((u >> 16) & 1u)) >> 16;
  return (u16)r;
}

__device__ __forceinline__ void gll16(const void* g, void* l) {
  __builtin_amdgcn_global_load_lds(
      (const __attribute__((address_space(1))) void*)g,
      (__attribute__((address_space(3))) void*)l, 16, 0, 0);
}

// ---------------- LayerNorm: x[B,P,D] fp32 -> xn[P,B,D] bf16 ----------------
__global__ __launch_bounds__(256) void ln_kernel(
    const float* __restrict__ x, const float* __restrict__ gamma,
    const float* __restrict__ beta, u16* __restrict__ xn) {
  const int wave = threadIdx.x >> 6, lane = threadIdx.x & 63;
  const int row = blockIdx.x * 4 + wave;         // 0..4095 = b*16+p
  const int b = row >> 4, p = row & 15;
  const float4* xr = (const float4*)(x + (size_t)row * DLAT);
  const float4* g4 = (const float4*)(gamma + (size_t)p * DLAT);
  const float4* b4 = (const float4*)(beta + (size_t)p * DLAT);
  float4 v[3];
  float s = 0.f, ss = 0.f;
#pragma unroll
  for (int j = 0; j < 3; ++j) {
    v[j] = xr[lane + j * 64];
    s += v[j].x + v[j].y + v[j].z + v[j].w;
    ss += v[j].x * v[j].x + v[j].y * v[j].y + v[j].z * v[j].z + v[j].w * v[j].w;
  }
#pragma unroll
  for (int o = 32; o; o >>= 1) { s += __shfl_xor(s, o); ss += __shfl_xor(ss, o); }
  const float mu = s * (1.f / 768.f);
  const float var = ss * (1.f / 768.f) - mu * mu;
  const float rstd = rsqrtf(var + 1e-5f);
  u16* xo = xn + ((size_t)(p * NB + b)) * DLAT;
#pragma unroll
  for (int j = 0; j < 3; ++j) {
    const int f = lane + j * 64;
    float4 g = g4[f], be = b4[f];
    float o0 = (v[j].x - mu) * rstd * g.x + be.x;
    float o1 = (v[j].y - mu) * rstd * g.y + be.y;
    float o2 = (v[j].z - mu) * rstd * g.z + be.z;
    float o3 = (v[j].w - mu) * rstd * g.w + be.w;
    uint2 w;
    w.x = (u32)f2b(o0) | ((u32)f2b(o1) << 16);
    w.y = (u32)f2b(o2) | ((u32)f2b(o3) << 16);
    *(uint2*)&xo[f * 4] = w;
  }
}

// ---------------- fc1: h = GELU(xn @ w1^T)  per part ----------------
// BM=256 (w1 read once), BN=64, BK=32. 4 waves, wave w -> rows [64w,64w+64).
// A via global_load_lds (swizzled source -> linear LDS), B reg-staged 2 ahead,
// raw s_barrier + counted vmcnt (6 vmem ops per K-step per thread).
__global__ __launch_bounds__(256, 2) void fc1_kernel(
    const u16* __restrict__ xn, const float* __restrict__ w1, u16* __restrict__ h) {
  const int bid = blockIdx.x;
  const int bs = (bid & 7) * 96 + (bid >> 3);    // XCD swizzle (768 = 8*96)
  const int p = bs / 48;
  const int n0 = (bs % 48) * 64;
  const int tid = threadIdx.x;
  const int lane = tid & 63, wave = tid >> 6;
  const int lanelo = lane & 15, lanehi = lane >> 4;

  const u16* Ap = xn + (size_t)p * NB * DLAT;
  const float* Bp = w1 + (size_t)p * HDIM * DLAT + (size_t)n0 * DLAT;

  __shared__ u16 As[3][256 * 32];   // 48 KiB, slot-swizzled, gll-filled
  __shared__ u16 Bs[2][64 * 32];    // 8 KiB, slot-swizzled, ds_write-filled

  // gll A: per-lane swizzled global source, wave-uniform LDS base
  int ag_off[4];
  const int ag_base = (256 * wave) * 8;          // u16 elems; +i*512
#pragma unroll
  for (int i = 0; i < 4; ++i) {
    int slot = 256 * wave + 64 * i + lane;
    int r = slot >> 2;
    int c = (slot & 3) ^ ((r >> 1) & 3);
    ag_off[i] = r * DLAT + c * 8;
  }
  // B global source (fp32): 2 rows per thread
  const float* bg0 = Bp + (size_t)(tid >> 3) * DLAT + (tid & 7) * 4;
  const float* bg1 = bg0 + (size_t)32 * DLAT;
  // B LDS store offsets (swizzled, 8B halves)
  int bso[2];
#pragma unroll
  for (int i = 0; i < 2; ++i) {
    int r = (tid >> 3) + 32 * i;
    int c = ((tid & 7) >> 1) ^ ((r >> 1) & 3);
    bso[i] = (r * 4 + c) * 8 + (tid & 1) * 4;
  }
  // fragment read offsets (kt-independent)
  int a_sl[4], b_sl[4];
#pragma unroll
  for (int m = 0; m < 4; ++m) {
    int r = wave * 64 + m * 16 + lanelo;
    a_sl[m] = (r * 4 + (lanehi ^ ((r >> 1) & 3))) * 8;
    int rb = m * 16 + lanelo;
    b_sl[m] = (rb * 4 + (lanehi ^ ((rb >> 1) & 3))) * 8;
  }

  f32x4 acc[4][4] = {};
  float4 bA0, bA1, bB0, bB1;
  const int NK = DLAT / 32;  // 24

  auto issue = [&](int kt, float4& r0, float4& r1) {
    const int k2 = kt * 32;
    u16* lb = &As[kt % 3][ag_base];
#pragma unroll
    for (int i = 0; i < 4; ++i) gll16(Ap + ag_off[i] + k2, lb + i * 512);
    asm volatile("" ::: "memory");               // keep glls before B loads
    r0 = *(const float4*)(bg0 + k2);
    r1 = *(const float4*)(bg1 + k2);
    asm volatile("" ::: "memory");               // pin issue order
  };

  auto step = [&](int kt, float4& r0, float4& r1) {
    if (kt + 1 < NK) asm volatile("s_waitcnt vmcnt(6)" ::: "memory");
    else             asm volatile("s_waitcnt vmcnt(0)" ::: "memory");
    {
      u16* bb = &Bs[kt & 1][0];
      uint2 w0, w1v;
      w0.x = (u32)f2b(r0.x) | ((u32)f2b(r0.y) << 16);
      w0.y = (u32)f2b(r0.z) | ((u32)f2b(r0.w) << 16);
      w1v.x = (u32)f2b(r1.x) | ((u32)f2b(r1.y) << 16);
      w1v.y = (u32)f2b(r1.z) | ((u32)f2b(r1.w) << 16);
      *(uint2*)&bb[bso[0]] = w0;
      *(uint2*)&bb[bso[1]] = w1v;
    }
    asm volatile("s_waitcnt lgkmcnt(0)" ::: "memory");
    __builtin_amdgcn_s_barrier();
    asm volatile("" ::: "memory");               // nothing moves above barrier
    if (kt + 2 < NK) issue(kt + 2, r0, r1);
    const u16* a_ = &As[kt % 3][0];
    const u16* b_ = &Bs[kt & 1][0];
    bf16x8 af[4], bf[4];
#pragma unroll
    for (int m = 0; m < 4; ++m) af[m] = *(const bf16x8*)&a_[a_sl[m]];
#pragma unroll
    for (int n = 0; n < 4; ++n) bf[n] = *(const bf16x8*)&b_[b_sl[n]];
#pragma unroll
    for (int m = 0; m < 4; ++m)
#pragma unroll
      for (int n = 0; n < 4; ++n)
        acc[m][n] = __builtin_amdgcn_mfma_f32_16x16x32_bf16(af[m], bf[n], acc[m][n], 0, 0, 0);
  };

  issue(0, bA0, bA1);
  issue(1, bB0, bB1);
  for (int kt = 0; kt < NK; kt += 2) {
    step(kt, bA0, bA1);
    step(kt + 1, bB0, bB1);
  }

  // epilogue: exact GELU, store bf16
  u16* hp = h + (size_t)p * NB * HDIM;
#pragma unroll
  for (int m = 0; m < 4; ++m) {
#pragma unroll
    for (int n = 0; n < 4; ++n) {
      const int col = n0 + n * 16 + lanelo;
#pragma unroll
      for (int r = 0; r < 4; ++r) {
        const int row = wave * 64 + m * 16 + lanehi * 4 + r;
        const float vv = acc[m][n][r];
        const float gel = 0.5f * vv * (1.f + erff(vv * 0.70710678118654752f));
        hp[(size_t)row * HDIM + col] = f2b(gel);
      }
    }
  }
}

// ---------------- fc2: out = h @ w2^T + b2, concat slices ----------------
// BM=64, BN=64, BK=32; 4 waves 2x2, each 32x32. Same pipeline, 3 vmem ops/step.
__global__ __launch_bounds__(256) void fc2_kernel(
    const u16* __restrict__ hbuf, const float* __restrict__ w2,
    const float* __restrict__ b2, float* __restrict__ out) {
  const int bid = blockIdx.x;
  const int bs = (bid & 7) * 32 + (bid >> 3);    // XCD swizzle (256 = 8*32)
  const int p = bs >> 4;
  const int mb = (bs >> 2) & 3;
  const int nb = bs & 3;
  const int odim = 100 + 10 * p;
  const int n0 = nb * 64;
  if (n0 >= odim) return;                        // uniform per block
  const int m0 = mb * 64;
  const int off = 100 * p + 5 * p * (p - 1);

  const int tid = threadIdx.x;
  const int lane = tid & 63, wave = tid >> 6;
  const int lanelo = lane & 15, lanehi = lane >> 4;
  const int wr = wave >> 1, wc = wave & 1;

  const u16* Ap = hbuf + (size_t)p * NB * HDIM + (size_t)m0 * HDIM;
  const float* Bp = w2 + (size_t)p * MAXO * HDIM;

  __shared__ u16 As[3][64 * 32];   // 12 KiB
  __shared__ u16 Bs[2][64 * 32];   // 8 KiB

  // gll A: one 16B chunk per thread per step
  int ag_off;
  const int ag_base = (64 * wave) * 8;
  {
    int slot = 64 * wave + lane;
    int r = slot >> 2;
    int c = (slot & 3) ^ ((r >> 1) & 3);
    ag_off = r * HDIM + c * 8;
  }
  // B global (fp32), rows clamped to allocation
  const int br0 = min(n0 + (tid >> 3), MAXO - 1);
  const int br1 = min(n0 + (tid >> 3) + 32, MAXO - 1);
  const float* bg0 = Bp + (size_t)br0 * HDIM + (tid & 7) * 4;
  const float* bg1 = Bp + (size_t)br1 * HDIM + (tid & 7) * 4;
  int bso[2];
#pragma unroll
  for (int i = 0; i < 2; ++i) {
    int r = (tid >> 3) + 32 * i;
    int c = ((tid & 7) >> 1) ^ ((r >> 1) & 3);
    bso[i] = (r * 4 + c) * 8 + (tid & 1) * 4;
  }
  int a_sl[2], b_sl[2];
#pragma unroll
  for (int m = 0; m < 2; ++m) {
    int r = wr * 32 + m * 16 + lanelo;
    a_sl[m] = (r * 4 + (lanehi ^ ((r >> 1) & 3))) * 8;
    int rb = wc * 32 + m * 16 + lanelo;
    b_sl[m] = (rb * 4 + (lanehi ^ ((rb >> 1) & 3))) * 8;
  }

  f32x4 acc[2][2] = {};
  float4 bA0, bA1, bB0, bB1;
  const int NK = HDIM / 32;  // 96

  auto issue = [&](int kt, float4& r0, float4& r1) {
    const int k2 = kt * 32;
    gll16(Ap + ag_off + k2, &As[kt % 3][ag_base]);
    asm volatile("" ::: "memory");
    r0 = *(const float4*)(bg0 + k2);
    r1 = *(const float4*)(bg1 + k2);
    asm volatile("" ::: "memory");
  };

  auto step = [&](int kt, float4& r0, float4& r1) {
    if (kt + 1 < NK) asm volatile("s_waitcnt vmcnt(3)" ::: "memory");
    else             asm volatile("s_waitcnt vmcnt(0)" ::: "memory");
    {
      u16* bb = &Bs[kt & 1][0];
      uint2 w0, w1v;
      w0.x = (u32)f2b(r0.x) | ((u32)f2b(r0.y) << 16);
      w0.y = (u32)f2b(r0.z) | ((u32)f2b(r0.w) << 16);
      w1v.x = (u32)f2b(r1.x) | ((u32)f2b(r1.y) << 16);
      w1v.y = (u32)f2b(r1.z) | ((u32)f2b(r1.w) << 16);
      *(uint2*)&bb[bso[0]] = w0;
      *(uint2*)&bb[bso[1]] = w1v;
    }
    asm volatile("s_waitcnt lgkmcnt(0)" ::: "memory");
    __builtin_amdgcn_s_barrier();
    asm volatile("" ::: "memory");
    if (kt + 2 < NK) issue(kt + 2, r0, r1);
    const u16* a_ = &As[kt % 3][0];
    const u16* b_ = &Bs[kt & 1][0];
    bf16x8 af[2], bf[2];
#pragma unroll
    for (int m = 0; m < 2; ++m) af[m] = *(const bf16x8*)&a_[a_sl[m]];
#pragma unroll
    for (int n = 0; n < 2; ++n) bf[n] = *(const bf16x8*)&b_[b_sl[n]];
#pragma unroll
    for (int m = 0; m < 2; ++m)
#pragma unroll
      for (int n = 0; n < 2; ++n)
        acc[m][n] = __builtin_amdgcn_mfma_f32_16x16x32_bf16(af[m], bf[n], acc[m][n], 0, 0, 0);
  };

  issue(0, bA0, bA1);
  issue(1, bB0, bB1);
  for (int kt = 0; kt < NK; kt += 2) {
    step(kt, bA0, bA1);
    step(kt + 1, bB0, bB1);
  }

  // epilogue: bias + masked store into concatenated output
#pragma unroll
  for (int m = 0; m < 2; ++m) {
#pragma unroll
    for (int n = 0; n < 2; ++n) {
      const int col = n0 + wc * 32 + n * 16 + lanelo;
      if (col < odim) {
        const float bias = b2[(size_t)p * MAXO + col];
#pragma unroll
        for (int r = 0; r < 4; ++r) {
          const int row = m0 + wr * 32 + m * 16 + lanehi * 4 + r;
          out[(size_t)row * TOT + off + col] = acc[m][n][r] + bias;
        }
      }
    }
  }
}

extern "C" void kernel_launch(void* const* d_in, const int* in_sizes, int n_in,
                              void* d_out, int out_size, void* d_ws, size_t ws_size,
                              hipStream_t stream) {
  const float* x = (const float*)d_in[0];
  const float* gamma = (const float*)d_in[1];
  const float* beta = (const float*)d_in[2];
  const float* w1 = (const float*)d_in[3];
  const float* w2 = (const float*)d_in[4];
  const float* b2 = (const float*)d_in[5];
  float* out = (float*)d_out;

  u16* xn = (u16*)d_ws;                             // [16][256][768] bf16
  u16* h = (u16*)d_ws + (size_t)NP * NB * DLAT;     // [16][256][3072] bf16

  ln_kernel<<<1024, 256, 0, stream>>>(x, gamma, beta, xn);
  fc1_kernel<<<NP * 48, 256, 0, stream>>>(xn, w1, h);
  fc2_kernel<<<NP * 16, 256, 0, stream>>>(h, w2, b2, out);
}